// Round 5
// baseline (216.068 us; speedup 1.0000x reference)
//
#include <hip/hip_runtime.h>
#include <hip/hip_bf16.h>
#include <stdint.h>

typedef __attribute__((ext_vector_type(8))) short bf16x8;
typedef __attribute__((ext_vector_type(4))) float f32x4;

#define DEVI static __device__ __forceinline__

// Problem sizes (fixed)
static constexpr int B_SZ = 4096, N_SZ = 128, H_SZ = 128, W_SZ = 64;

// ws layout (bytes), all 16B aligned
static constexpr size_t OFF_W1 = 0;                      // 128 * 128*128 bf16 = 4 MB (UNswizzled [n][c][h])
static constexpr size_t OFF_W2 = OFF_W1 + 4194304;       // 128 * 64*128 bf16 = 2 MB (UNswizzled [n][w][k])
static constexpr size_t OFF_F1 = OFF_W2 + 2097152;       // 128*128 bf16 = 32 KB (swizzled [o][h])
static constexpr size_t OFF_F2 = OFF_F1 + 32768;         // 384*128 bf16 = 96 KB (swizzled [o][j])
static constexpr size_t OFF_H  = OFF_F2 + 98304;         // 4096*128 bf16 = 1 MB (per-128-row tile, swizzled)

DEVI unsigned short f2bf(float f) {
  union { __hip_bfloat16 b; unsigned short u; } cv;
  cv.b = __float2bfloat16(f);
  return cv.u;
}
DEVI float bf2f(unsigned short u) {
  union { unsigned int i; float f; } cv;
  cv.i = ((unsigned int)u) << 16;
  return cv.f;
}

// Read one MFMA fragment (8 contiguous bf16 along k) from a swizzled LDS tile.
// Tile layout: row stride 256B; 16B slot s stored at (s ^ (row&7)).
DEVI bf16x8 frag_ld(const unsigned char* base, int row, int kslot) {
  return *reinterpret_cast<const bf16x8*>(base + row * 256 + (((kslot ^ (row & 7)) << 4)));
}
// Unswizzled fragment read (global memory, 256B rows).
DEVI bf16x8 gfrag_ld(const unsigned char* base, int row, int kslot) {
  return *reinterpret_cast<const bf16x8*>(base + row * 256 + (kslot << 4));
}

// Stage an nrows x 128 fp32 tile (row stride in elems) into swizzled bf16 LDS.
DEVI void stage_f32_tile(const float* src, int row_stride, unsigned char* dst, int tid, int nrows) {
  for (int t = tid; t < nrows * 16; t += 256) {
    int row = t >> 4, s = t & 15;
    const float* p = src + (size_t)row * row_stride + s * 8;
    union { unsigned short u[8]; uint4 v; } pk;
#pragma unroll
    for (int j = 0; j < 8; ++j) pk.u[j] = f2bf(p[j]);
    *reinterpret_cast<uint4*>(dst + row * 256 + ((s ^ (row & 7)) << 4)) = pk.v;
  }
}

// ---------------- prep: convert+transpose weights into ws (bf16) ----------------
__global__ __launch_bounds__(256) void prep_kernel(const float* __restrict__ rw1,
                                                   const float* __restrict__ rw2,
                                                   const float* __restrict__ fc1w,
                                                   const float* __restrict__ fc2w,
                                                   unsigned char* __restrict__ ws) {
  const int T_W1 = 128 * 128 * 16;  // (n,s,c): W1t[n][c][h=s*8+j] = rw1[n][h][c]  (c = output h)
  const int T_W2 = 128 * 64 * 16;   // (n,s,w): W2t[n][w][k=s*8+j] = rw2[n][k][w]
  const int T_F1 = 128 * 16;        // (o,s):   F1s[o][h]          = fc1w[o][h]  (swizzled)
  const int T_F2 = 384 * 16;
  int id = blockIdx.x * 256 + threadIdx.x;
  if (id < T_W1) {
    int c = id & 127, rest = id >> 7;
    int s = rest & 15, n = rest >> 4;
    const float* src = rw1 + (size_t)n * 16384 + (size_t)(s * 8) * 128 + c;
    union { unsigned short u[8]; uint4 v; } pk;
#pragma unroll
    for (int j = 0; j < 8; ++j) pk.u[j] = f2bf(src[(size_t)j * 128]);
    size_t dst = OFF_W1 + ((size_t)n * 128 + c) * 256 + (size_t)(s << 4);
    *reinterpret_cast<uint4*>(ws + dst) = pk.v;
    return;
  }
  id -= T_W1;
  if (id < T_W2) {
    int w = id & 63, rest = id >> 6;
    int s = rest & 15, n = rest >> 4;
    const float* src = rw2 + (size_t)n * 8192 + (size_t)(s * 8) * 64 + w;
    union { unsigned short u[8]; uint4 v; } pk;
#pragma unroll
    for (int j = 0; j < 8; ++j) pk.u[j] = f2bf(src[(size_t)j * 64]);
    size_t dst = OFF_W2 + ((size_t)n * 64 + w) * 256 + (size_t)(s << 4);
    *reinterpret_cast<uint4*>(ws + dst) = pk.v;
    return;
  }
  id -= T_W2;
  if (id < T_F1) {
    int s = id & 15, o = id >> 4;
    const float* src = fc1w + (size_t)o * 128 + s * 8;
    union { unsigned short u[8]; uint4 v; } pk;
#pragma unroll
    for (int j = 0; j < 8; ++j) pk.u[j] = f2bf(src[j]);
    *reinterpret_cast<uint4*>(ws + OFF_F1 + (size_t)o * 256 + ((s ^ (o & 7)) << 4)) = pk.v;
    return;
  }
  id -= T_F1;
  if (id < T_F2) {
    int s = id & 15, o = id >> 4;
    const float* src = fc2w + (size_t)o * 128 + s * 8;
    union { unsigned short u[8]; uint4 v; } pk;
#pragma unroll
    for (int j = 0; j < 8; ++j) pk.u[j] = f2bf(src[j]);
    *reinterpret_cast<uint4*>(ws + OFF_F2 + (size_t)o * 256 + ((s ^ (o & 7)) << 4)) = pk.v;
  }
}

// ---------------- recon v5: 64-b x 4-n blocks, direct coalesced fp32 output ----------------
// Per node n: G1' C1t[k][b] = W1t . SE^T ; relu+bias -> hn ; G2' C2t[w][b] = W2t . hn^T.
// G2 results accumulate in LDS sOUT[b][w'][nl]; after 4 nodes one flush pass stores
// float4 out3[b][w][n0..n0+3]. Chunk-group swizzle keeps the 4 chunks of each 64B
// output line on one XCD (L2 write merge) and makes weights L2-resident (768KB/XCD).
__global__ __launch_bounds__(256, 2) void recon_kernel(const float* __restrict__ se,
                                                       const float* __restrict__ rb1,
                                                       const float* __restrict__ rb2,
                                                       const unsigned char* __restrict__ ws,
                                                       float* __restrict__ out3) {
  __shared__ unsigned char sSE[16384];   // SE 64-row tile (swizzled rows b, 256B), reused per n
  __shared__ unsigned char sHN[16384];   // hn 64-row tile (swizzled rows b, 256B)
  __shared__ unsigned char sOUT[32768];  // [b 64][w^(b&7) 64][nl 4] bf16

  const int tid = threadIdx.x;
  const int id = blockIdx.x;                          // 0..2047
  const int chunk = ((id & 7) << 2) | ((id >> 3) & 3);  // 0..31 ; XCD = chunk>>2
  const int btile = id >> 5;                            // 0..63
  const int n0 = chunk * 4;
  const int b0 = btile * 64;

  const int wave = tid >> 6, lane = tid & 63;
  const int wm = wave >> 1, wq = wave & 1;  // wm: out-row half, wq: b half (32 each)
  const int lr = lane & 15, lk = lane >> 4;

  // stage SE(n0)
  stage_f32_tile(se + ((size_t)b0 * 128 + n0) * 128, 128 * 128, sSE, tid, 64);
  __syncthreads();

  float4 fra[4], frb[4];  // next-n SE staging registers

  auto issue_pref = [&](int n) {
    const float* sb = se + ((size_t)b0 * 128 + n) * 128;
#pragma unroll
    for (int k = 0; k < 4; ++k) {
      int c = tid + k * 256;
      int row = c >> 4, s = c & 15;
      const float* p = sb + (size_t)row * 16384 + s * 8;
      fra[k] = *reinterpret_cast<const float4*>(p);
      frb[k] = *reinterpret_cast<const float4*>(p + 4);
    }
  };
  auto write_pref = [&]() {
#pragma unroll
    for (int k = 0; k < 4; ++k) {
      int c = tid + k * 256;
      int row = c >> 4, s = c & 15;
      union { unsigned short u[8]; uint4 v; } pk;
#pragma unroll
      for (int j = 0; j < 4; ++j) pk.u[j] = f2bf(fra[k][j]);
#pragma unroll
      for (int j = 0; j < 4; ++j) pk.u[4 + j] = f2bf(frb[k][j]);
      *reinterpret_cast<uint4*>(sSE + row * 256 + ((s ^ (row & 7)) << 4)) = pk.v;
    }
  };

#pragma unroll 1
  for (int nl = 0; nl < 4; ++nl) {
    const int n = n0 + nl;

    // [A] weights -> VGPR fragments (L2-hot), biases
    const unsigned char* w1b = ws + OFF_W1 + (size_t)n * 32768;
    const unsigned char* w2b = ws + OFF_W2 + (size_t)n * 16384;
    bf16x8 w1f[4][4], w2f[2][4];
#pragma unroll
    for (int m = 0; m < 4; ++m)
#pragma unroll
      for (int kk = 0; kk < 4; ++kk)
        w1f[m][kk] = gfrag_ld(w1b, wm * 64 + m * 16 + lr, kk * 4 + lk);
#pragma unroll
    for (int m = 0; m < 2; ++m)
#pragma unroll
      for (int kk = 0; kk < 4; ++kk)
        w2f[m][kk] = gfrag_ld(w2b, wm * 32 + m * 16 + lr, kk * 4 + lk);
    float bias1[4][4], bias2[2][4];
#pragma unroll
    for (int m = 0; m < 4; ++m)
#pragma unroll
      for (int j = 0; j < 4; ++j) bias1[m][j] = rb1[(size_t)n * 128 + wm * 64 + m * 16 + lk * 4 + j];
#pragma unroll
    for (int m = 0; m < 2; ++m)
#pragma unroll
      for (int j = 0; j < 4; ++j) bias2[m][j] = rb2[(size_t)n * 64 + wm * 32 + m * 16 + lk * 4 + j];

    if (nl == 0) issue_pref(n0 + 1);  // SE(n0+1), consumed at this iter's write_pref

    // [B] GEMM1': 128(k) x 64(b) x 128(h); wave owns 64k x 32b
    f32x4 acc[4][2] = {};
#pragma unroll
    for (int kk = 0; kk < 4; ++kk) {
      const int slot = kk * 4 + lk;
      bf16x8 bv[2];
#pragma unroll
      for (int q = 0; q < 2; ++q) bv[q] = frag_ld(sSE, wq * 32 + q * 16 + lr, slot);
#pragma unroll
      for (int m = 0; m < 4; ++m)
#pragma unroll
        for (int q = 0; q < 2; ++q)
          acc[m][q] = __builtin_amdgcn_mfma_f32_16x16x32_bf16(w1f[m][kk], bv[q], acc[m][q], 0, 0, 0);
    }
    __syncthreads();  // [C] G1 readers done: sSE free; prev G2's sHN reads done

    // [D] epilogue1: hn[b][k] = relu(C1t[k][b] + rb1[k]) -> bf16 into sHN
    // lane: b = wq*32+q*16+lr, k = wm*64+m*16+lk*4+j -> 8B write
#pragma unroll
    for (int m = 0; m < 4; ++m) {
      const int k0 = wm * 64 + m * 16 + lk * 4;
      const int s16 = k0 >> 3, half = (k0 >> 2) & 1;
#pragma unroll
      for (int q = 0; q < 2; ++q) {
        const int b = wq * 32 + q * 16 + lr;
        union { unsigned short u[4]; uint2 v; } pk;
#pragma unroll
        for (int j = 0; j < 4; ++j) {
          float v = acc[m][q][j] + bias1[m][j];
          v = v > 0.f ? v : 0.f;
          pk.u[j] = f2bf(v);
        }
        *reinterpret_cast<uint2*>(sHN + b * 256 + ((s16 ^ (b & 7)) << 4) + half * 8) = pk.v;
      }
    }

    // [E] stage SE(n+1) into sSE (overlaps epi1; G1 readers drained at [C])
    if (nl < 3) write_pref();
    __syncthreads();  // [F] sHN + sSE(n+1) ready

    // issue SE(n+2) loads: long lead (G2+epi2+G1+epi1 before consumption)
    if (nl < 2) issue_pref(n0 + nl + 2);

    // [G] GEMM2': 64(w) x 64(b) x 128(k); wave owns 32w x 32b
    f32x4 acc2[2][2] = {};
#pragma unroll
    for (int kk = 0; kk < 4; ++kk) {
      const int slot = kk * 4 + lk;
      bf16x8 bv[2];
#pragma unroll
      for (int q = 0; q < 2; ++q) bv[q] = frag_ld(sHN, wq * 32 + q * 16 + lr, slot);
#pragma unroll
      for (int m = 0; m < 2; ++m)
#pragma unroll
        for (int q = 0; q < 2; ++q)
          acc2[m][q] = __builtin_amdgcn_mfma_f32_16x16x32_bf16(w2f[m][kk], bv[q], acc2[m][q], 0, 0, 0);
    }

    // [H] epilogue2: bf16 into sOUT[b][w^(b&7)][nl] (disjoint across n, no barrier)
#pragma unroll
    for (int m = 0; m < 2; ++m) {
#pragma unroll
      for (int q = 0; q < 2; ++q) {
        const int b = wq * 32 + q * 16 + lr;
#pragma unroll
        for (int j = 0; j < 4; ++j) {
          const int w = wm * 32 + m * 16 + lk * 4 + j;
          float v = acc2[m][q][j] + bias2[m][j];
          *reinterpret_cast<unsigned short*>(sOUT + b * 512 + ((w ^ (b & 7)) << 3) + nl * 2) = f2bf(v);
        }
      }
    }
  }
  __syncthreads();  // all epi2 writes visible

  // flush: out3[b][w][n0..n0+3] as float4 (16B granules; chunk-group shares XCD for line merge)
  {
    const int w = lane;
    float* dst = out3 + (size_t)b0 * 8192 + w * 128 + n0;
#pragma unroll
    for (int bb = 0; bb < 16; ++bb) {
      const int b = wave * 16 + bb;
      union { uint2 v; unsigned short u[4]; } rd;
      rd.v = *reinterpret_cast<const uint2*>(sOUT + b * 512 + ((w ^ (b & 7)) << 3));
      float4 o;
      o.x = bf2f(rd.u[0]);
      o.y = bf2f(rd.u[1]);
      o.z = bf2f(rd.u[2]);
      o.w = bf2f(rd.u[3]);
      *reinterpret_cast<float4*>(dst + (size_t)b * 8192) = o;
    }
  }
}

// ---------------- forecast stage 1: h = relu(emb @ fc1^T + b1) -> ws (bf16, tile-swizzled) ----------------
__global__ __launch_bounds__(256) void f1_kernel(const float* __restrict__ emb,
                                                 const float* __restrict__ fc1b,
                                                 const unsigned char* __restrict__ ws,
                                                 unsigned char* __restrict__ hsw) {
  __shared__ unsigned char sA[32768];
  __shared__ unsigned char sB[32768];
  const int tid = threadIdx.x;
  const int bt = blockIdx.x;
  const int b0 = bt * 128;
  {
    const uint4* wp = reinterpret_cast<const uint4*>(ws + OFF_F1);
    uint4* d = reinterpret_cast<uint4*>(sB);
    for (int c = tid; c < 2048; c += 256) d[c] = wp[c];
  }
  stage_f32_tile(emb + (size_t)b0 * 128, 128, sA, tid, 128);
  __syncthreads();

  const int wave = tid >> 6, lane = tid & 63;
  const int wm = wave >> 1, wn = wave & 1;
  const int lr = lane & 15, lk = lane >> 4;

  f32x4 acc[4][4] = {};
#pragma unroll
  for (int kk = 0; kk < 4; ++kk) {
    bf16x8 af[4], bfv[4];
#pragma unroll
    for (int m = 0; m < 4; ++m) af[m] = frag_ld(sA, wm * 64 + m * 16 + lr, kk * 4 + lk);
#pragma unroll
    for (int q = 0; q < 4; ++q) bfv[q] = frag_ld(sB, wn * 64 + q * 16 + lr, kk * 4 + lk);
#pragma unroll
    for (int m = 0; m < 4; ++m)
#pragma unroll
      for (int q = 0; q < 4; ++q)
        acc[m][q] = __builtin_amdgcn_mfma_f32_16x16x32_bf16(af[m], bfv[q], acc[m][q], 0, 0, 0);
  }

  unsigned char* tile = hsw + (size_t)bt * 32768;
#pragma unroll
  for (int q = 0; q < 4; ++q) {
    int c = wn * 64 + q * 16 + lr;
    float bias = fc1b[c];
#pragma unroll
    for (int m = 0; m < 4; ++m) {
#pragma unroll
      for (int j = 0; j < 4; ++j) {
        int r = wm * 64 + m * 16 + lk * 4 + j;
        float v = acc[m][q][j] + bias;
        v = v > 0.f ? v : 0.f;
        *reinterpret_cast<unsigned short*>(tile + r * 256 + ((c * 2) ^ ((r & 7) << 4))) = f2bf(v);
      }
    }
  }
}

// ---------------- forecast stage 2: forecast = h @ fc2^T + b2 ----------------
__global__ __launch_bounds__(256) void f2_kernel(const unsigned char* __restrict__ hsw,
                                                 const unsigned char* __restrict__ f2s,
                                                 const float* __restrict__ fc2b,
                                                 float* __restrict__ out2) {
  __shared__ unsigned char sA[32768];
  __shared__ unsigned char sB[32768];
  const int tid = threadIdx.x;
  const int bt = blockIdx.x;      // 0..31
  const int ch = blockIdx.y;      // 0..2 (chunks of 128 output cols)
  const int b0 = bt * 128;
  {
    const uint4* ap = reinterpret_cast<const uint4*>(hsw + (size_t)bt * 32768);
    uint4* da = reinterpret_cast<uint4*>(sA);
    for (int c = tid; c < 2048; c += 256) da[c] = ap[c];
    const uint4* bp = reinterpret_cast<const uint4*>(f2s + (size_t)ch * 32768);
    uint4* db = reinterpret_cast<uint4*>(sB);
    for (int c = tid; c < 2048; c += 256) db[c] = bp[c];
  }
  __syncthreads();

  const int wave = tid >> 6, lane = tid & 63;
  const int wm = wave >> 1, wn = wave & 1;
  const int lr = lane & 15, lk = lane >> 4;

  f32x4 acc[4][4] = {};
#pragma unroll
  for (int kk = 0; kk < 4; ++kk) {
    bf16x8 af[4], bfv[4];
#pragma unroll
    for (int m = 0; m < 4; ++m) af[m] = frag_ld(sA, wm * 64 + m * 16 + lr, kk * 4 + lk);
#pragma unroll
    for (int q = 0; q < 4; ++q) bfv[q] = frag_ld(sB, wn * 64 + q * 16 + lr, kk * 4 + lk);
#pragma unroll
    for (int m = 0; m < 4; ++m)
#pragma unroll
      for (int q = 0; q < 4; ++q)
        acc[m][q] = __builtin_amdgcn_mfma_f32_16x16x32_bf16(af[m], bfv[q], acc[m][q], 0, 0, 0);
  }

#pragma unroll
  for (int q = 0; q < 4; ++q) {
    int o = ch * 128 + wn * 64 + q * 16 + lr;
    float bias = fc2b[o];
#pragma unroll
    for (int m = 0; m < 4; ++m) {
#pragma unroll
      for (int j = 0; j < 4; ++j) {
        int r = wm * 64 + m * 16 + lk * 4 + j;
        out2[(size_t)(b0 + r) * 384 + o] = acc[m][q][j] + bias;
      }
    }
  }
}

extern "C" void kernel_launch(void* const* d_in, const int* in_sizes, int n_in,
                              void* d_out, int out_size, void* d_ws, size_t ws_size,
                              hipStream_t stream) {
  const float* emb  = (const float*)d_in[0];
  const float* se   = (const float*)d_in[1];
  const float* slog = (const float*)d_in[2];
  const float* fc1w = (const float*)d_in[3];
  const float* fc1b = (const float*)d_in[4];
  const float* fc2w = (const float*)d_in[5];
  const float* fc2b = (const float*)d_in[6];
  const float* rw1  = (const float*)d_in[7];
  const float* rb1  = (const float*)d_in[8];
  const float* rw2  = (const float*)d_in[9];
  const float* rb2  = (const float*)d_in[10];
  float* out = (float*)d_out;
  unsigned char* ws = (unsigned char*)d_ws;

  // output 0: passthrough logits (B*N fp32)
  hipMemcpyAsync(out, slog, (size_t)B_SZ * N_SZ * sizeof(float),
                 hipMemcpyDeviceToDevice, stream);

  // weight prep (bf16 convert + transpose into ws)
  prep_kernel<<<1568, 256, 0, stream>>>(rw1, rw2, fc1w, fc2w, ws);

  // forecast head
  f1_kernel<<<32, 256, 0, stream>>>(emb, fc1b, ws, ws + OFF_H);
  f2_kernel<<<dim3(32, 3), 256, 0, stream>>>(ws + OFF_H, ws + OFF_F2, fc2b,
                                             out + (size_t)B_SZ * N_SZ);

  // reconstruction heads (dominant): single-phase direct-fp32 recon, no transpose pass
  float* out3 = out + (size_t)B_SZ * N_SZ + (size_t)B_SZ * 384;
  recon_kernel<<<2048, 256, 0, stream>>>(se, rb1, rb2, ws, out3);
}